// Round 11
// baseline (512.481 us; speedup 1.0000x reference)
//
#include <hip/hip_runtime.h>
#include <hip/hip_bf16.h>
#include <math.h>

typedef __attribute__((ext_vector_type(8))) short s8v;
typedef __attribute__((ext_vector_type(4))) float f4v;
typedef __attribute__((ext_vector_type(4))) double d4;
typedef __hip_bfloat16 bf16;

#define NEGF (-3.40282346638528859812e+38f)
#define DSMEM 37376  // 2*32*73*8: As+Bs, single-buffered BK=32 (R8 winner)

enum { EPI_F32 = 0, EPI_BIAS, EPI_BRELU_BF16, EPI_BF16, EPI_FINAL };

__device__ __forceinline__ float wred_sum(float v) {
#pragma unroll
  for (int m = 1; m < 64; m <<= 1) v += __shfl_xor(v, m, 64);
  return v;
}

// ---------------------------------------------------------------------------
// f64 MFMA GEMM body (R8 winner): 64x64 tile, BK=32, single LDS buffer for
// A+B with register prefetch. [R9: A-direct regressed — LDS round-trip IS the
// coalescing mechanism.] A: m=lane&15,k=lane>>4; B: n=lane&15,k=lane>>4;
// D (f64 STRIDED rows): col=lane&15, row=(lane>>4)+4*reg [R4-verified].
// ---------------------------------------------------------------------------
template <int EPI>
__device__ __forceinline__ void dgemm_body(char* smem, int bx, int by, int bz,
    const double* __restrict__ A, const double* __restrict__ Bt, void* __restrict__ C,
    int K, int ldC, long sA, long sB, long sC, const double* __restrict__ bias, double scale) {
  double (*As)[73] = (double(*)[73])smem;
  double (*Bs)[73] = (double(*)[73])(smem + 32 * 73 * 8);
  const double* a = A + (long)bz * sA;
  const double* b = Bt + (long)bz * sB;
  int tid = threadIdx.x;
  int wv = tid >> 6, lane = tid & 63;
  int lm = tid >> 2;
  int lk = (tid & 3) << 3;
  long arow = (long)(bx * 64 + lm) * K + lk;
  long brow = (long)(by * 64 + lm) * K + lk;
  int fm = lane & 15, fk = lane >> 4;
  d4 acc[4] = {};
  {
    d4 a0 = *(const d4*)&a[arow], a1 = *(const d4*)&a[arow + 4];
    d4 b0 = *(const d4*)&b[brow], b1 = *(const d4*)&b[brow + 4];
#pragma unroll
    for (int j = 0; j < 4; j++) {
      As[lk + j][lm] = a0[j];
      As[lk + 4 + j][lm] = a1[j];
      Bs[lk + j][lm] = b0[j];
      Bs[lk + 4 + j][lm] = b1[j];
    }
  }
  __syncthreads();
  int nit = K >> 5;
  for (int it = 0; it < nit; it++) {
    d4 a0, a1, b0, b1;
    bool pf = (it + 1 < nit);
    if (pf) {
      long ko = (long)(it + 1) << 5;
      a0 = *(const d4*)&a[arow + ko];
      a1 = *(const d4*)&a[arow + ko + 4];
      b0 = *(const d4*)&b[brow + ko];
      b1 = *(const d4*)&b[brow + ko + 4];
    }
#pragma unroll
    for (int kk = 0; kk < 8; kk++) {
      double af = As[kk * 4 + fk][wv * 16 + fm];
#pragma unroll
      for (int nt = 0; nt < 4; nt++) {
        double bf = Bs[kk * 4 + fk][nt * 16 + fm];
        acc[nt] = __builtin_amdgcn_mfma_f64_16x16x4f64(af, bf, acc[nt], 0, 0, 0);
      }
    }
    if (pf) {
      __syncthreads();
#pragma unroll
      for (int j = 0; j < 4; j++) {
        As[lk + j][lm] = a0[j];
        As[lk + 4 + j][lm] = a1[j];
        Bs[lk + j][lm] = b0[j];
        Bs[lk + 4 + j][lm] = b1[j];
      }
      __syncthreads();
    }
  }
#pragma unroll
  for (int nt = 0; nt < 4; nt++) {
    int gn = by * 64 + nt * 16 + (lane & 15);
#pragma unroll
    for (int rg = 0; rg < 4; rg++) {
      int gm = bx * 64 + wv * 16 + (lane >> 4) + 4 * rg;
      double v = acc[nt][rg];
      if (bias) v += bias[gn];
      long ci = (long)bz * sC + (long)gm * ldC + gn;
      if (EPI == 0) ((double*)C)[ci] = v;
      else if (EPI == 1) ((double*)C)[ci] = v > 0.0 ? v : 0.0;
      else ((float*)C)[ci] = (float)(v * scale);
    }
  }
}

// f64 split-K body for skinny 2048x64x1024 (by = K-chunk id), partials to P.
__device__ __forceinline__ void dksplit_body(char* smem, int bx, int by,
    const double* __restrict__ A, const double* __restrict__ Bt, double* __restrict__ P, int K, int KC) {
  double (*As)[73] = (double(*)[73])smem;
  double (*Bs)[73] = (double(*)[73])(smem + 32 * 73 * 8);
  int tid = threadIdx.x;
  int wv = tid >> 6, lane = tid & 63;
  int lm = tid >> 2, lk = (tid & 3) << 3;
  long kbeg = (long)by * KC;
  long arow = (long)(bx * 64 + lm) * K + kbeg + lk;
  long brow = (long)lm * K + kbeg + lk;
  int fm = lane & 15, fk = lane >> 4;
  d4 acc[4] = {};
  {
    d4 a0 = *(const d4*)&A[arow], a1 = *(const d4*)&A[arow + 4];
    d4 b0 = *(const d4*)&Bt[brow], b1 = *(const d4*)&Bt[brow + 4];
#pragma unroll
    for (int j = 0; j < 4; j++) {
      As[lk + j][lm] = a0[j];
      As[lk + 4 + j][lm] = a1[j];
      Bs[lk + j][lm] = b0[j];
      Bs[lk + 4 + j][lm] = b1[j];
    }
  }
  __syncthreads();
  int nit = KC >> 5;
  for (int it = 0; it < nit; it++) {
    d4 a0, a1, b0, b1;
    bool pf = (it + 1 < nit);
    if (pf) {
      long ko = (long)(it + 1) << 5;
      a0 = *(const d4*)&A[arow + ko];
      a1 = *(const d4*)&A[arow + ko + 4];
      b0 = *(const d4*)&Bt[brow + ko];
      b1 = *(const d4*)&Bt[brow + ko + 4];
    }
#pragma unroll
    for (int kk = 0; kk < 8; kk++) {
      double af = As[kk * 4 + fk][wv * 16 + fm];
#pragma unroll
      for (int nt = 0; nt < 4; nt++) {
        double bf = Bs[kk * 4 + fk][nt * 16 + fm];
        acc[nt] = __builtin_amdgcn_mfma_f64_16x16x4f64(af, bf, acc[nt], 0, 0, 0);
      }
    }
    if (pf) {
      __syncthreads();
#pragma unroll
      for (int j = 0; j < 4; j++) {
        As[lk + j][lm] = a0[j];
        As[lk + 4 + j][lm] = a1[j];
        Bs[lk + j][lm] = b0[j];
        Bs[lk + 4 + j][lm] = b1[j];
      }
      __syncthreads();
    }
  }
  double* p = P + (long)by * 131072;
#pragma unroll
  for (int nt = 0; nt < 4; nt++) {
    int gn = nt * 16 + (lane & 15);
#pragma unroll
    for (int rg = 0; rg < 4; rg++) {
      int gm = bx * 64 + wv * 16 + (lane >> 4) + 4 * rg;
      p[(long)gm * 64 + gn] = acc[nt][rg];
    }
  }
}

// bf16 MFMA GEMM body, 64x64 tile, double-buffered (16 KB within smem).
template <int EPI>
__device__ __forceinline__ void bgemm_body(char* smem, int bx, int by, int bz,
    const bf16* __restrict__ A, const bf16* __restrict__ B, void* __restrict__ C,
    int K, int ldC, long sA, long sB, long sC,
    const float* __restrict__ bias, const void* __restrict__ aux) {
  short (*Ahs)[2048] = (short(*)[2048])smem;
  short (*Bhs)[2048] = (short(*)[2048])(smem + 2 * 2048 * 2);
  const short* ah = (const short*)A + (long)bz * sA;
  const short* bh = (const short*)B + (long)bz * sB;
  int tid = threadIdx.x;
  int wv_ = tid >> 6, lane = tid & 63;
  int lrow = tid >> 2, lcol = (tid & 3) << 3;
  int lidx = lrow * 32 + lcol;
  long abase = (long)(bx * 64 + lrow) * K + lcol;
  long bbase = (long)(by * 64 + lrow) * K + lcol;
  int frow = lane & 15, fk = (lane >> 4) << 3;
  int aoff = (wv_ * 16 + frow) * 32 + fk;
  f4v acc[4] = {};
  {
    s8v avh = *(const s8v*)&ah[abase];
    s8v bvh = *(const s8v*)&bh[bbase];
    *(s8v*)&Ahs[0][lidx] = avh;
    *(s8v*)&Bhs[0][lidx] = bvh;
  }
  __syncthreads();
  int nit = K >> 5, buf = 0;
  for (int it = 0; it < nit; it++) {
    s8v avh, bvh;
    bool pf = (it + 1 < nit);
    if (pf) {
      long ko = (long)(it + 1) << 5;
      avh = *(const s8v*)&ah[abase + ko];
      bvh = *(const s8v*)&bh[bbase + ko];
    }
    s8v afh = *(const s8v*)&Ahs[buf][aoff];
#pragma unroll
    for (int nt = 0; nt < 4; nt++) {
      s8v bfh = *(const s8v*)&Bhs[buf][(nt * 16 + frow) * 32 + fk];
      acc[nt] = __builtin_amdgcn_mfma_f32_16x16x32_bf16(afh, bfh, acc[nt], 0, 0, 0);
    }
    if (pf) {
      *(s8v*)&Ahs[buf ^ 1][lidx] = avh;
      *(s8v*)&Bhs[buf ^ 1][lidx] = bvh;
      __syncthreads();
      buf ^= 1;
    }
  }
  int rb = bx * 64 + wv_ * 16 + ((lane >> 4) << 2);
#pragma unroll
  for (int nt = 0; nt < 4; nt++) {
    int gn = by * 64 + nt * 16 + (lane & 15);
#pragma unroll
    for (int rg = 0; rg < 4; rg++) {
      int gm = rb + rg;
      float v = acc[nt][rg];
      long ci = (long)bz * sC + (long)gm * ldC + gn;
      if (EPI == EPI_F32) ((float*)C)[ci] = v;
      else if (EPI == EPI_BIAS) ((float*)C)[ci] = v + bias[gn];
      else if (EPI == EPI_BRELU_BF16) ((bf16*)C)[ci] = __float2bfloat16(fmaxf(v + bias[gn], 0.f));
      else if (EPI == EPI_BF16) ((bf16*)C)[ci] = __float2bfloat16(v);
      else if (EPI == EPI_FINAL)
        ((float*)C)[ci] = v + bias[gm] + (float)((const double*)aux)[(long)gn * 512 + gm];
    }
  }
}

// Weight-cast ladder (everything NOT needed by the conv GEMM itself).
__device__ __forceinline__ void prep_elem(long i,
    const float* __restrict__ wq, const float* __restrict__ wk, const float* __restrict__ wv,
    const float* __restrict__ wst, const float* __restrict__ bst, const float* __restrict__ kc_b1,
    const float* __restrict__ kc_b2, const float* __restrict__ kc_w1, const float* __restrict__ kc_w2,
    const float* __restrict__ vc_w1, const float* __restrict__ vc_w2, const float* __restrict__ w_comb,
    const float* __restrict__ w_out, double* __restrict__ wqk64, bf16* __restrict__ wvs,
    float* __restrict__ bias2, double* __restrict__ kb1_64, double* __restrict__ kb2_64,
    double* __restrict__ kw1_64, double* __restrict__ kw2_64, bf16* __restrict__ vw1b,
    bf16* __restrict__ vw2b, bf16* __restrict__ wcombb, bf16* __restrict__ woutb) {
  if (i < 524288) {
    int r = (int)(i >> 9), c = (int)(i & 511);
    wqk64[i] = (double)((r < 512) ? wq[i] : wk[(r - 512) * 512 + c]);
    return;
  }
  i -= 524288;
  if (i < 294912) {
    int r = (int)(i >> 9), c = (int)(i & 511);
    float v = 0.f;
    if (r < 512) v = wv[i];
    else if (r < 536) v = wst[(r - 512) * 512 + c];
    wvs[i] = __float2bfloat16(v);
    if (i < 576) bias2[i] = (i >= 512 && i < 536) ? bst[i - 512] : 0.f;
    return;
  }
  i -= 294912;
  if (i < 1088) {
    if (i < 1024) kb1_64[i] = (double)kc_b1[i];
    else kb2_64[i - 1024] = (double)kc_b2[i - 1024];
    return;
  }
  i -= 1088;
  if (i < 1048576) { kw1_64[i] = (double)kc_w1[i]; return; }
  i -= 1048576;
  if (i < 65536) { kw2_64[i] = (double)kc_w2[i]; return; }
  i -= 65536;
  if (i < 1048576) { vw1b[i] = __float2bfloat16(vc_w1[i]); return; }
  i -= 1048576;
  if (i < 65536) { vw2b[i] = __float2bfloat16(vc_w2[i]); return; }
  i -= 65536;
  if (i < 262144) { wcombb[i] = __float2bfloat16(w_comb[i]); return; }
  i -= 262144;
  if (i < 262144) woutb[i] = __float2bfloat16(w_out[i]);
}
#define PREP_TOTAL 3572800l

// ---- standalone kernels ----
template <int EPI>
__global__ __launch_bounds__(256) void dgemm_bt(
    const double* __restrict__ A, const double* __restrict__ Bt, void* __restrict__ C,
    int K, int ldC, long sA, long sB, long sC, const double* __restrict__ bias, double scale) {
  __shared__ char smem[DSMEM];
  dgemm_body<EPI>(smem, blockIdx.x, blockIdx.y, blockIdx.z, A, Bt, C, K, ldC, sA, sB, sC, bias, scale);
}

template <int EPI>
__global__ __launch_bounds__(256) void gemm_bt(
    const bf16* __restrict__ A, const bf16* __restrict__ B, void* __restrict__ C,
    int K, int ldC, long sA, long sB, long sC,
    const float* __restrict__ bias, const void* __restrict__ aux) {
  __shared__ char smem[4 * 2048 * 2];
  bgemm_body<EPI>(smem, blockIdx.x, blockIdx.y, blockIdx.z, A, B, C, K, ldC, sA, sB, sC, bias, aux);
}

// conv f64 GEMM (y<8) + weight-prep casts (y>=8) in one dispatch.
__global__ __launch_bounds__(256) void k_conv_prep(
    const double* __restrict__ xt64, const double* __restrict__ win64, double* __restrict__ xs64,
    const double* __restrict__ b_in64,
    const float* __restrict__ wq, const float* __restrict__ wk, const float* __restrict__ wv,
    const float* __restrict__ wst, const float* __restrict__ bst, const float* __restrict__ kc_b1,
    const float* __restrict__ kc_b2, const float* __restrict__ kc_w1, const float* __restrict__ kc_w2,
    const float* __restrict__ vc_w1, const float* __restrict__ vc_w2, const float* __restrict__ w_comb,
    const float* __restrict__ w_out, double* __restrict__ wqk64, bf16* __restrict__ wvs,
    float* __restrict__ bias2, double* __restrict__ kb1_64, double* __restrict__ kb2_64,
    double* __restrict__ kw1_64, double* __restrict__ kw2_64, bf16* __restrict__ vw1b,
    bf16* __restrict__ vw2b, bf16* __restrict__ wcombb, bf16* __restrict__ woutb) {
  __shared__ char smem[DSMEM];
  if (blockIdx.y < 8) {
    dgemm_body<0>(smem, blockIdx.x, blockIdx.y, 0, xt64, win64, xs64, 512, 512, 0, 0, 0, b_in64, 1.0);
  } else {
    long base = (((long)(blockIdx.y - 8) * 64 + blockIdx.x) * 256) + threadIdx.x;
    for (long i = base; i < PREP_TOTAL; i += 16l * 64 * 256)
      prep_elem(i, wq, wk, wv, wst, bst, kc_b1, kc_b2, kc_w1, kc_w2, vc_w1, vc_w2, w_comb, w_out,
                wqk64, wvs, bias2, kb1_64, kb2_64, kw1_64, kw2_64, vw1b, vw2b, wcombb, woutb);
  }
}

// ---------------------------------------------------------------------------
// qk f64 GEMM (by<16) with FUSED repack epilogue: each lane holds exactly the
// (n, d) elements the old k_repackA64 re-read from HBM. q-blocks (by<8) write
// qh64 + roped rq; k-blocks (by 8..15) write roped rk + kin64 (+k_pos).
// RoPE pair partner comes from __shfl_xor(lane,1). bf16 T2 GEMM at by>=16.
// Value flow identical to R10's repackA64 (same f64 copy, same float ops).
// ---------------------------------------------------------------------------
__global__ __launch_bounds__(256) void k_fused_qk_t2(
    const double* __restrict__ h64, const double* __restrict__ wqk,
    double* __restrict__ qh, double* __restrict__ kin,
    float* __restrict__ rq, float* __restrict__ rk, const float* __restrict__ kpos,
    const bf16* __restrict__ hbf, const bf16* __restrict__ wvs, float* __restrict__ T2,
    const float* __restrict__ bias2) {
  __shared__ char smem[DSMEM];
  if (blockIdx.y >= 16) {
    bgemm_body<EPI_BIAS>(smem, blockIdx.x, blockIdx.y - 16, 0, hbf, wvs, T2, 512, 576, 0, 0, 0, bias2,
                         nullptr);
    return;
  }
  double (*As)[73] = (double(*)[73])smem;
  double (*Bs)[73] = (double(*)[73])(smem + 32 * 73 * 8);
  int bx = blockIdx.x, by = blockIdx.y;
  int tid = threadIdx.x;
  int wv = tid >> 6, lane = tid & 63;
  int lm = tid >> 2, lk = (tid & 3) << 3;
  long arow = (long)(bx * 64 + lm) * 512 + lk;
  long brow = (long)(by * 64 + lm) * 512 + lk;
  int fm = lane & 15, fk = lane >> 4;
  d4 acc[4] = {};
  {
    d4 a0 = *(const d4*)&h64[arow], a1 = *(const d4*)&h64[arow + 4];
    d4 b0 = *(const d4*)&wqk[brow], b1 = *(const d4*)&wqk[brow + 4];
#pragma unroll
    for (int j = 0; j < 4; j++) {
      As[lk + j][lm] = a0[j];
      As[lk + 4 + j][lm] = a1[j];
      Bs[lk + j][lm] = b0[j];
      Bs[lk + 4 + j][lm] = b1[j];
    }
  }
  __syncthreads();
  for (int it = 0; it < 16; it++) {
    d4 a0, a1, b0, b1;
    bool pf = (it + 1 < 16);
    if (pf) {
      long ko = (long)(it + 1) << 5;
      a0 = *(const d4*)&h64[arow + ko];
      a1 = *(const d4*)&h64[arow + ko + 4];
      b0 = *(const d4*)&wqk[brow + ko];
      b1 = *(const d4*)&wqk[brow + ko + 4];
    }
#pragma unroll
    for (int kk = 0; kk < 8; kk++) {
      double af = As[kk * 4 + fk][wv * 16 + fm];
#pragma unroll
      for (int nt = 0; nt < 4; nt++) {
        double bf = Bs[kk * 4 + fk][nt * 16 + fm];
        acc[nt] = __builtin_amdgcn_mfma_f64_16x16x4f64(af, bf, acc[nt], 0, 0, 0);
      }
    }
    if (pf) {
      __syncthreads();
#pragma unroll
      for (int j = 0; j < 4; j++) {
        As[lk + j][lm] = a0[j];
        As[lk + 4 + j][lm] = a1[j];
        Bs[lk + j][lm] = b0[j];
        Bs[lk + 4 + j][lm] = b1[j];
      }
      __syncthreads();
    }
  }
  bool isq = by < 8;
  int h = isq ? by : by - 8;
#pragma unroll
  for (int nt = 0; nt < 4; nt++) {
    int dloc = nt * 16 + fm;
    int d2 = dloc >> 1;
    float inv = powf(10000.f, -(float)(2 * d2) / 64.f);
#pragma unroll
    for (int rg = 0; rg < 4; rg++) {
      int n = bx * 64 + wv * 16 + fk + 4 * rg;
      double v = acc[nt][rg];
      float ang = (float)n * inv;
      float sv = sinf(ang), cv = cosf(ang);
      float vf = (float)v;
      float vp = __shfl_xor(vf, 1, 64);
      float rr = (dloc & 1) ? (vf * cv + vp * sv) : (vf * cv - vp * sv);
      long oi = ((long)h * 4096 + n) * 64 + dloc;
      if (isq) {
        qh[oi] = v;
        rq[oi] = rr;
      } else {
        rk[oi] = rr;
        kin[(((long)h * 256 + (n >> 4)) * 16 + (n & 15)) * 64 + dloc] =
            v + (double)kpos[(h * 16 + (n & 15)) * 64 + dloc];
      }
    }
  }
}

// slim v-repack: T2 v-part -> vvb (f32 head-major) + vin (bf16 + v_pos).
__global__ void k_repackV(const float* __restrict__ T2, const float* __restrict__ vpos,
                          float* __restrict__ vvv, bf16* __restrict__ vin) {
  int e = blockIdx.x * 256 + threadIdx.x;  // 8*4096*64
  int d = e & 63, n = (e >> 6) & 4095, h = e >> 18;
  float v0 = T2[(long)n * 576 + h * 64 + d];
  vvv[((long)h * 4096 + n) * 64 + d] = v0;
  vin[(((long)h * 256 + (n >> 4)) * 16 + (n & 15)) * 64 + d] =
      __float2bfloat16(v0 + vpos[(h * 16 + (n & 15)) * 64 + d]);
}

__global__ __launch_bounds__(256) void k_fused_mlp1(
    const double* __restrict__ kin, const double* __restrict__ kw1, double* __restrict__ hidk,
    const double* __restrict__ kb1, const bf16* __restrict__ vin, const bf16* __restrict__ vw1,
    bf16* __restrict__ hidv, const float* __restrict__ vb1) {
  __shared__ char smem[DSMEM];
  if (blockIdx.y < 16)
    dgemm_body<1>(smem, blockIdx.x, blockIdx.y, 0, kin, kw1, hidk, 1024, 1024, 0, 0, 0, kb1, 1.0);
  else
    bgemm_body<EPI_BRELU_BF16>(smem, blockIdx.x, blockIdx.y - 16, 0, vin, vw1, hidv, 1024, 1024, 0, 0, 0,
                               vb1, nullptr);
}

__global__ __launch_bounds__(256) void k_fused_mlp2(
    const double* __restrict__ hidk, const double* __restrict__ kw2, double* __restrict__ kpart,
    const bf16* __restrict__ hidv, const bf16* __restrict__ vw2, float* __restrict__ cvc,
    const float* __restrict__ vb2) {
  __shared__ char smem[DSMEM];
  if (blockIdx.y < 8)
    dksplit_body(smem, blockIdx.x, blockIdx.y, hidk, kw2, kpart, 1024, 128);
  else
    bgemm_body<EPI_BIAS>(smem, blockIdx.x, 0, 0, hidv, vw2, cvc, 1024, 64, 0, 0, 0, vb2, nullptr);
}

// x (512,4096) f32 -> xt (4096,512) f64; y==16 slab casts win64/b_in64.
__global__ void k_transpose64(const float* __restrict__ x, double* __restrict__ xt,
                              const float* __restrict__ w_in, const float* __restrict__ b_in,
                              double* __restrict__ win64, double* __restrict__ b_in64) {
  if (blockIdx.y == 16) {
    int tid = threadIdx.y * 32 + threadIdx.x;
    long base = (long)blockIdx.x * 256 + tid;
    for (long i = base; i < 262656; i += 128l * 256) {
      if (i < 262144) win64[i] = (double)w_in[i];
      else b_in64[i - 262144] = (double)b_in[i - 262144];
    }
    return;
  }
  __shared__ float t[32][33];
  int n0 = blockIdx.x * 32, c0 = blockIdx.y * 32;
  int tx = threadIdx.x, ty = threadIdx.y;
#pragma unroll
  for (int r = ty; r < 32; r += 8) t[r][tx] = x[(long)(c0 + r) * 4096 + n0 + tx];
  __syncthreads();
#pragma unroll
  for (int r = ty; r < 32; r += 8) xt[(long)(n0 + r) * 512 + c0 + tx] = (double)t[tx][r];
}

__global__ __launch_bounds__(256) void k_rmsnorm64(const double* __restrict__ xs, const float* __restrict__ g,
                                                   double* __restrict__ h64, bf16* __restrict__ hbf) {
  int n = blockIdx.x, t = threadIdx.x;
  const double* row = xs + (long)n * 512;
  double a = row[t], b = row[t + 256];
  double ss = a * a + b * b;
#pragma unroll
  for (int m = 1; m < 64; m <<= 1) ss += __shfl_xor(ss, m, 64);
  __shared__ double red[4];
  if ((t & 63) == 0) red[t >> 6] = ss;
  __syncthreads();
  double tot = red[0] + red[1] + red[2] + red[3];
  double r = 1.0 / sqrt(tot / 512.0 + 1e-6);
  double h0 = a * r * (double)g[t], h1 = b * r * (double)g[t + 256];
  long o = (long)n * 512 + t;
  h64[o] = h0;
  h64[o + 256] = h1;
  hbf[o] = __float2bfloat16((float)h0);
  hbf[o + 256] = __float2bfloat16((float)h1);
}

// split-K partials (8x 2048x64) + cvc + mem rows -> ckb64 (8,320,64 f64), cvtb (8,64,288 bf16).
__global__ void k_repackB64(const double* __restrict__ kpart, const float* __restrict__ cvc,
                            const float* __restrict__ mem_k, const float* __restrict__ mem_v,
                            const double* __restrict__ kb2, double* __restrict__ ckb,
                            bf16* __restrict__ cvtb) {
  int g = blockIdx.x * 256 + threadIdx.x;
  if (g < 8 * 320 * 64) {
    int d = g & 63, j = (g >> 6) % 320, h = g / (320 * 64);
    double v = 0.0;
    if (j == 0) v = (double)mem_k[h * 64 + d];
    else if (j < 257) {
      long ri = ((long)h * 256 + (j - 1)) * 64 + d;
      double s = 0.0;
#pragma unroll
      for (int p = 0; p < 8; p++) s += kpart[(long)p * 131072 + ri];
      v = s + kb2[d];
    }
    ckb[g] = v;
  }
  if (g < 8 * 64 * 288) {
    int j = g % 288, d = (g / 288) & 63, h = g / (288 * 64);
    float v = 0.f;
    if (j == 0) v = mem_v[h * 64 + d];
    else if (j < 257) v = cvc[((long)h * 256 + (j - 1)) * 64 + d];
    cvtb[g] = __float2bfloat16(v);
  }
}

// Per (h,i) row: compressed softmax -> probs (bf16), and exact top-k block selection.
__global__ __launch_bounds__(256) void k_selsm(const float* __restrict__ csim, bf16* __restrict__ pb,
                                               int4* __restrict__ selb) {
  int r = blockIdx.x * 4 + (threadIdx.x >> 6);
  int lane = threadIdx.x & 63;
  int i = r & 4095;
  const float* row = csim + (long)r * 320;
  int nv = i / 16 + 1;
  float s[5], e[5];
  float mx = -INFINITY;
#pragma unroll
  for (int t = 0; t < 5; t++) {
    int j = lane + 64 * t;
    float v = (j < nv) ? row[j] : -INFINITY;
    s[t] = v;
    mx = fmaxf(mx, v);
  }
#pragma unroll
  for (int m = 1; m < 64; m <<= 1) mx = fmaxf(mx, __shfl_xor(mx, m, 64));
  float sum = 0.f;
#pragma unroll
  for (int t = 0; t < 5; t++) {
    int j = lane + 64 * t;
    e[t] = (j < nv) ? __expf(s[t] - mx) : 0.f;
    sum += e[t];
  }
  sum = wred_sum(sum);
  float rinv = 1.f / sum;
  bf16* prow = pb + (long)r * 288;
#pragma unroll
  for (int t = 0; t < 5; t++) {
    int j = lane + 64 * t;
    if (j < 288) prow[j] = __float2bfloat16((j < nv) ? e[t] * rinv : 0.f);
  }
  int nvb = i >> 1;
  int nmv = (nvb + 7) >> 3;
  float vm[4];
  float bestv = -INFINITY;
  int bestm = 0x7fffffff;
#pragma unroll
  for (int t = 0; t < 4; t++) {
    int m = lane + 64 * t;
    float v = -INFINITY;
    if (m < nmv) v = (m + 1 < nv) ? row[m + 1] : NEGF;
    vm[t] = v;
    if (v > bestv) { bestv = v; bestm = m; }
  }
#pragma unroll
  for (int mk = 1; mk < 64; mk <<= 1) {
    float ov = __shfl_xor(bestv, mk, 64);
    int om = __shfl_xor(bestm, mk, 64);
    if (ov > bestv || (ov == bestv && om < bestm)) { bestv = ov; bestm = om; }
  }
  int m0 = bestm;
  int cnt0 = min(8, nvb - 8 * m0);
  float rv = -INFINITY;
  int rm = 0x7fffffff;
#pragma unroll
  for (int t = 0; t < 4; t++) {
    int m = lane + 64 * t;
    if (m != m0 && vm[t] > rv) { rv = vm[t]; rm = m; }
  }
#pragma unroll
  for (int mk = 1; mk < 64; mk <<= 1) {
    float ov = __shfl_xor(rv, mk, 64);
    int om = __shfl_xor(rm, mk, 64);
    if (ov > rv || (ov == rv && om < rm)) { rv = ov; rm = om; }
  }
  float Ml = fmaxf(-1000.f, bestv);
  float z = 0.f;
#pragma unroll
  for (int t = 0; t < 4; t++) {
    int m = lane + 64 * t;
    if (m < nmv) z += (float)min(8, nvb - 8 * m) * expf(vm[t] - Ml);
  }
  z = wred_sum(z) + expf(-1000.f - Ml);
  int fb0 = 0, fb1 = 0, mk0 = 0, mk1 = 0;
  if (nmv > 0) {
    float sv0 = expf(bestv - Ml) / z;
    fb0 = 8 * m0;
    mk0 = sv0 > 1e-10f;
    if (cnt0 >= 2) { fb1 = fb0 + 1; mk1 = mk0; }
    else if (nmv > 1) {
      float sv1 = expf(rv - Ml) / z;
      fb1 = 8 * rm;
      mk1 = sv1 > 1e-10f;
    }
  }
  if (lane == 0) selb[r] = make_int4(fb0, fb1, mk0, mk1);
}

// ---------------------------------------------------------------------------
// FUSED pv GEMM + fine/slide/combine: block (bx, h) computes co rows
// bx*64..+63 for head h (bf16 MFMA, K=288) into LDS, then runs the fineslide
// for exactly those rows (wave w handles rows w*16..w*16+15, 64 lanes = d).
// Removes the co HBM round-trip and the standalone k_fineslide dispatch.
// ---------------------------------------------------------------------------
__global__ __launch_bounds__(256) void k_pv_fine(
    const bf16* __restrict__ pb, const bf16* __restrict__ cvtb,
    const float* __restrict__ rq, const float* __restrict__ rk, const float* __restrict__ vv,
    const int4* __restrict__ selb, const float* __restrict__ T2, bf16* __restrict__ comb) {
  __shared__ char smem[16384];
  __shared__ float cosm[64][65];
  int bx = blockIdx.x, h = blockIdx.y;
  short (*Ahs)[2048] = (short(*)[2048])smem;
  short (*Bhs)[2048] = (short(*)[2048])(smem + 8192);
  const short* ah = (const short*)pb + (long)h * 4096 * 288;
  const short* bh = (const short*)cvtb + (long)h * 64 * 288;
  int tid = threadIdx.x, wv_ = tid >> 6, lane = tid & 63;
  int lrow = tid >> 2, lcol = (tid & 3) << 3;
  int lidx = lrow * 32 + lcol;
  long abase = (long)(bx * 64 + lrow) * 288 + lcol;
  long bbase = (long)lrow * 288 + lcol;
  int frow = lane & 15, fk = (lane >> 4) << 3;
  int aoff = (wv_ * 16 + frow) * 32 + fk;
  f4v acc[4] = {};
  {
    s8v avh = *(const s8v*)&ah[abase];
    s8v bvh = *(const s8v*)&bh[bbase];
    *(s8v*)&Ahs[0][lidx] = avh;
    *(s8v*)&Bhs[0][lidx] = bvh;
  }
  __syncthreads();
  int buf = 0;
  for (int it = 0; it < 9; it++) {
    s8v avh, bvh;
    bool pf = (it + 1 < 9);
    if (pf) {
      long ko = (long)(it + 1) << 5;
      avh = *(const s8v*)&ah[abase + ko];
      bvh = *(const s8v*)&bh[bbase + ko];
    }
    s8v afh = *(const s8v*)&Ahs[buf][aoff];
#pragma unroll
    for (int nt = 0; nt < 4; nt++) {
      s8v bfh = *(const s8v*)&Bhs[buf][(nt * 16 + frow) * 32 + fk];
      acc[nt] = __builtin_amdgcn_mfma_f32_16x16x32_bf16(afh, bfh, acc[nt], 0, 0, 0);
    }
    if (pf) {
      *(s8v*)&Ahs[buf ^ 1][lidx] = avh;
      *(s8v*)&Bhs[buf ^ 1][lidx] = bvh;
      __syncthreads();
      buf ^= 1;
    }
  }
  int rb = wv_ * 16 + ((lane >> 4) << 2);
#pragma unroll
  for (int nt = 0; nt < 4; nt++)
#pragma unroll
    for (int rg = 0; rg < 4; rg++) cosm[rb + rg][nt * 16 + (lane & 15)] = acc[nt][rg];
  __syncthreads();
  long hb = (long)h * 4096 * 64;
  int d = lane;
  for (int rr = 0; rr < 16; rr++) {
    int rloc = wv_ * 16 + rr;
    int i = bx * 64 + rloc;
    float qd = rq[hb + (long)i * 64 + d];
    int4 s4 = selb[((long)h << 12) + i];
    int dg = i >> 1;
    int tok[6] = {2 * s4.x, 2 * s4.x + 1, 2 * s4.y, 2 * s4.y + 1, 2 * dg, 2 * dg + 1};
    int ok6[6] = {s4.z, s4.z, s4.w, s4.w, 1, (i & 1)};
    float sim[6], val[6];
#pragma unroll
    for (int j = 0; j < 6; j++) {
      float kd = rk[hb + (long)tok[j] * 64 + d];
      val[j] = vv[hb + (long)tok[j] * 64 + d];
      float p = wred_sum(qd * kd);
      sim[j] = ok6[j] ? p * 0.125f : NEGF;
    }
    float mx = sim[0];
#pragma unroll
    for (int j = 1; j < 6; j++) mx = fmaxf(mx, sim[j]);
    float den = 0.f, fo = 0.f;
#pragma unroll
    for (int j = 0; j < 6; j++) {
      float e_ = __expf(sim[j] - mx);
      den += e_;
      fo += e_ * val[j];
    }
    fo /= den;
    float ssim[9], sval[9];
#pragma unroll
    for (int t = 0; t < 9; t++) {
      int tk = i - 8 + t;
      int okt = tk >= 0;
      int tc = okt ? tk : 0;
      float kd = rk[hb + (long)tc * 64 + d];
      sval[t] = okt ? vv[hb + (long)tc * 64 + d] : 0.f;
      float p = wred_sum(qd * kd);
      ssim[t] = okt ? p * 0.125f : NEGF;
    }
    float mx2 = ssim[8];
#pragma unroll
    for (int t = 0; t < 8; t++) mx2 = fmaxf(mx2, ssim[t]);
    float den2 = 0.f, so = 0.f;
#pragma unroll
    for (int t = 0; t < 9; t++) {
      float e_ = __expf(ssim[t] - mx2);
      den2 += e_;
      so += e_ * sval[t];
    }
    so /= den2;
    const float* gb = T2 + (long)i * 576 + 512 + h * 3;
    float g0 = 1.f / (1.f + __expf(-gb[0]));
    float g1 = 1.f / (1.f + __expf(-gb[1]));
    float g2 = 1.f / (1.f + __expf(-gb[2]));
    float cd = cosm[rloc][d];
    comb[(long)i * 512 + h * 64 + d] = __float2bfloat16(g0 * cd + g1 * fo + g2 * so);
  }
}

extern "C" void kernel_launch(void* const* d_in, const int* in_sizes, int n_in, void* d_out, int out_size,
                              void* d_ws, size_t ws_size, hipStream_t stream) {
  (void)in_sizes; (void)n_in; (void)out_size; (void)ws_size;
  const float* x = (const float*)d_in[0];
  const float* w_in = (const float*)d_in[1];
  const float* b_in = (const float*)d_in[2];
  const float* g_norm = (const float*)d_in[3];
  const float* wq = (const float*)d_in[4];
  const float* wk = (const float*)d_in[5];
  const float* wv = (const float*)d_in[6];
  const float* k_pos = (const float*)d_in[7];
  const float* v_pos = (const float*)d_in[8];
  const float* mem_k = (const float*)d_in[9];
  const float* mem_v = (const float*)d_in[10];
  const float* kc_w1 = (const float*)d_in[11];
  const float* kc_b1 = (const float*)d_in[12];
  const float* kc_w2 = (const float*)d_in[13];
  const float* kc_b2 = (const float*)d_in[14];
  const float* vc_w1 = (const float*)d_in[15];
  const float* vc_b1 = (const float*)d_in[16];
  const float* vc_w2 = (const float*)d_in[17];
  const float* vc_b2 = (const float*)d_in[18];
  const float* w_strat = (const float*)d_in[19];
  const float* b_strat = (const float*)d_in[20];
  const float* w_comb = (const float*)d_in[21];
  const float* w_out = (const float*)d_in[22];
  const float* b_out = (const float*)d_in[23];

  char* wsp = (char*)d_ws;
  size_t off = 0;
  auto alloc = [&](size_t b) -> void* {
    void* p = wsp + off;
    off += (b + 255) & ~(size_t)255;
    return p;
  };
  double* xs64 = (double*)alloc(4096l * 512 * 8);
  double* h64 = (double*)alloc(4096l * 512 * 8);
  bf16* hbf = (bf16*)alloc(4096l * 512 * 2);
  double* win64 = (double*)alloc(512l * 512 * 8);
  double* wqk64 = (double*)alloc(1024l * 512 * 8);
  bf16* wvs = (bf16*)alloc(576l * 512 * 2);
  float* bias2 = (float*)alloc(576 * 4);
  double* b_in64 = (double*)alloc(512 * 8);
  double* kb1_64 = (double*)alloc(1024 * 8);
  double* kb2_64 = (double*)alloc(64 * 8);
  float* T2 = (float*)alloc(4096l * 576 * 4);
  float* csim = (float*)alloc(8l * 4096 * 320 * 4);
  double* qh64 = (double*)alloc(8l * 4096 * 64 * 8);
  float* rq = (float*)alloc(8l * 4096 * 64 * 4);
  float* rk = (float*)alloc(8l * 4096 * 64 * 4);
  float* vvb = (float*)alloc(8l * 4096 * 64 * 4);
  double* xt64 = (double*)alloc(4096l * 512 * 8);  // reused later as hidk64
  double* hidk64 = xt64;
  char* kinpb = (char*)alloc(2048l * 1024 * 8 + 2048l * 1024 * 2);  // kin64+vin, later pb
  double* kin64 = (double*)kinpb;
  bf16* vinb = (bf16*)(kinpb + 2048l * 1024 * 8);
  bf16* pb = (bf16*)kinpb;
  double* kw1_64 = (double*)alloc(1024l * 1024 * 8);
  double* kw2_64 = (double*)alloc(64l * 1024 * 8);
  bf16* vw1b = (bf16*)alloc(1024l * 1024 * 2);
  bf16* vw2b = (bf16*)alloc(64l * 1024 * 2);
  bf16* hidv = (bf16*)alloc(2048l * 1024 * 2);
  float* cvc = (float*)alloc(2048l * 64 * 4);
  double* ckb64 = (double*)alloc(8l * 320 * 64 * 8);
  bf16* cvtb = (bf16*)alloc(8l * 64 * 288 * 2);
  int4* selb = (int4*)alloc(32768l * 16);
  bf16* comb = (bf16*)alloc(4096l * 512 * 2);
  bf16* zb = (bf16*)alloc(4096l * 512 * 2);
  bf16* wcombb = (bf16*)alloc(512l * 512 * 2);
  bf16* woutb = (bf16*)alloc(512l * 512 * 2);
  double* kpart = (double*)alloc(8l * 2048 * 64 * 8);  // split-K partials

  // ---- transpose + conv-weight cast ----
  k_transpose64<<<dim3(128, 17), dim3(32, 8), 0, stream>>>(x, xt64, w_in, b_in, win64, b_in64);
  // ---- conv (f64) + all remaining weight prep in one dispatch ----
  k_conv_prep<<<dim3(64, 24), 256, 0, stream>>>(xt64, win64, xs64, b_in64, wq, wk, wv, w_strat, b_strat,
                                                kc_b1, kc_b2, kc_w1, kc_w2, vc_w1, vc_w2, w_comb, w_out,
                                                wqk64, wvs, bias2, kb1_64, kb2_64, kw1_64, kw2_64, vw1b,
                                                vw2b, wcombb, woutb);
  k_rmsnorm64<<<4096, 256, 0, stream>>>(xs64, g_norm, h64, hbf);
  // ---- qk GEMM with fused repack epilogue (+ T2 bf16 GEMM) ----
  k_fused_qk_t2<<<dim3(64, 25, 1), 256, 0, stream>>>(h64, wqk64, qh64, kin64, rq, rk, k_pos, hbf, wvs, T2,
                                                     bias2);
  k_repackV<<<8192, 256, 0, stream>>>(T2, v_pos, vvb, vinb);
  k_fused_mlp1<<<dim3(32, 32, 1), 256, 0, stream>>>(kin64, kw1_64, hidk64, kb1_64, vinb, vw1b, hidv, vc_b1);
  k_fused_mlp2<<<dim3(32, 9, 1), 256, 0, stream>>>(hidk64, kw2_64, kpart, hidv, vw2b, cvc, vc_b2);
  k_repackB64<<<640, 256, 0, stream>>>(kpart, cvc, mem_k, mem_v, kb2_64, ckb64, cvtb);
  dgemm_bt<2><<<dim3(64, 5, 8), 256, 0, stream>>>(qh64, ckb64, csim, 64, 320, 4096l * 64, 320l * 64,
                                                  4096l * 320, nullptr, 0.125);
  // ---- selection + fused pv/fine/slide/combine ----
  k_selsm<<<8192, 256, 0, stream>>>(csim, pb, selb);
  k_pv_fine<<<dim3(64, 8), 256, 0, stream>>>(pb, cvtb, rq, rk, vvb, selb, T2, comb);
  // ---- output mixing ----
  gemm_bt<EPI_BF16><<<dim3(64, 8, 1), 256, 0, stream>>>(comb, wcombb, zb, 512, 512, 0, 0, 0, nullptr, nullptr);
  gemm_bt<EPI_FINAL><<<dim3(8, 64, 1), 256, 0, stream>>>(woutb, zb, d_out, 512, 4096, 0, 0, 0, b_out, xs64);
}

// Round 12
// 485.409 us; speedup vs baseline: 1.0558x; 1.0558x over previous
//
#include <hip/hip_runtime.h>
#include <hip/hip_bf16.h>
#include <math.h>

typedef __attribute__((ext_vector_type(8))) short s8v;
typedef __attribute__((ext_vector_type(4))) float f4v;
typedef __attribute__((ext_vector_type(4))) double d4;
typedef __hip_bfloat16 bf16;

#define NEGF (-3.40282346638528859812e+38f)
#define DSMEM 37376  // 2*32*73*8: As+Bs, single-buffered BK=32 (R8 winner)

enum { EPI_F32 = 0, EPI_BIAS, EPI_BRELU_BF16, EPI_BF16, EPI_FINAL };

__device__ __forceinline__ float wred_sum(float v) {
#pragma unroll
  for (int m = 1; m < 64; m <<= 1) v += __shfl_xor(v, m, 64);
  return v;
}

// ---------------------------------------------------------------------------
// f64 MFMA GEMM body (R8 winner): 64x64 tile, BK=32, single LDS buffer for
// A+B with register prefetch. A: m=lane&15,k=lane>>4; B: n=lane&15,k=lane>>4;
// D (f64 STRIDED rows): col=lane&15, row=(lane>>4)+4*reg [R4-verified].
// ---------------------------------------------------------------------------
template <int EPI>
__device__ __forceinline__ void dgemm_body(char* smem, int bx, int by, int bz,
    const double* __restrict__ A, const double* __restrict__ Bt, void* __restrict__ C,
    int K, int ldC, long sA, long sB, long sC, const double* __restrict__ bias, double scale) {
  double (*As)[73] = (double(*)[73])smem;
  double (*Bs)[73] = (double(*)[73])(smem + 32 * 73 * 8);
  const double* a = A + (long)bz * sA;
  const double* b = Bt + (long)bz * sB;
  int tid = threadIdx.x;
  int wv = tid >> 6, lane = tid & 63;
  int lm = tid >> 2;
  int lk = (tid & 3) << 3;
  long arow = (long)(bx * 64 + lm) * K + lk;
  long brow = (long)(by * 64 + lm) * K + lk;
  int fm = lane & 15, fk = lane >> 4;
  d4 acc[4] = {};
  {
    d4 a0 = *(const d4*)&a[arow], a1 = *(const d4*)&a[arow + 4];
    d4 b0 = *(const d4*)&b[brow], b1 = *(const d4*)&b[brow + 4];
#pragma unroll
    for (int j = 0; j < 4; j++) {
      As[lk + j][lm] = a0[j];
      As[lk + 4 + j][lm] = a1[j];
      Bs[lk + j][lm] = b0[j];
      Bs[lk + 4 + j][lm] = b1[j];
    }
  }
  __syncthreads();
  int nit = K >> 5;
  for (int it = 0; it < nit; it++) {
    d4 a0, a1, b0, b1;
    bool pf = (it + 1 < nit);
    if (pf) {
      long ko = (long)(it + 1) << 5;
      a0 = *(const d4*)&a[arow + ko];
      a1 = *(const d4*)&a[arow + ko + 4];
      b0 = *(const d4*)&b[brow + ko];
      b1 = *(const d4*)&b[brow + ko + 4];
    }
#pragma unroll
    for (int kk = 0; kk < 8; kk++) {
      double af = As[kk * 4 + fk][wv * 16 + fm];
#pragma unroll
      for (int nt = 0; nt < 4; nt++) {
        double bf = Bs[kk * 4 + fk][nt * 16 + fm];
        acc[nt] = __builtin_amdgcn_mfma_f64_16x16x4f64(af, bf, acc[nt], 0, 0, 0);
      }
    }
    if (pf) {
      __syncthreads();
#pragma unroll
      for (int j = 0; j < 4; j++) {
        As[lk + j][lm] = a0[j];
        As[lk + 4 + j][lm] = a1[j];
        Bs[lk + j][lm] = b0[j];
        Bs[lk + 4 + j][lm] = b1[j];
      }
      __syncthreads();
    }
  }
#pragma unroll
  for (int nt = 0; nt < 4; nt++) {
    int gn = by * 64 + nt * 16 + (lane & 15);
#pragma unroll
    for (int rg = 0; rg < 4; rg++) {
      int gm = bx * 64 + wv * 16 + (lane >> 4) + 4 * rg;
      double v = acc[nt][rg];
      if (bias) v += bias[gn];
      long ci = (long)bz * sC + (long)gm * ldC + gn;
      if (EPI == 0) ((double*)C)[ci] = v;
      else if (EPI == 1) ((double*)C)[ci] = v > 0.0 ? v : 0.0;
      else ((float*)C)[ci] = (float)(v * scale);
    }
  }
}

// f64 split-K body for skinny 2048x64x1024 (by = K-chunk id), partials to P.
__device__ __forceinline__ void dksplit_body(char* smem, int bx, int by,
    const double* __restrict__ A, const double* __restrict__ Bt, double* __restrict__ P, int K, int KC) {
  double (*As)[73] = (double(*)[73])smem;
  double (*Bs)[73] = (double(*)[73])(smem + 32 * 73 * 8);
  int tid = threadIdx.x;
  int wv = tid >> 6, lane = tid & 63;
  int lm = tid >> 2, lk = (tid & 3) << 3;
  long kbeg = (long)by * KC;
  long arow = (long)(bx * 64 + lm) * K + kbeg + lk;
  long brow = (long)lm * K + kbeg + lk;
  int fm = lane & 15, fk = lane >> 4;
  d4 acc[4] = {};
  {
    d4 a0 = *(const d4*)&A[arow], a1 = *(const d4*)&A[arow + 4];
    d4 b0 = *(const d4*)&Bt[brow], b1 = *(const d4*)&Bt[brow + 4];
#pragma unroll
    for (int j = 0; j < 4; j++) {
      As[lk + j][lm] = a0[j];
      As[lk + 4 + j][lm] = a1[j];
      Bs[lk + j][lm] = b0[j];
      Bs[lk + 4 + j][lm] = b1[j];
    }
  }
  __syncthreads();
  int nit = KC >> 5;
  for (int it = 0; it < nit; it++) {
    d4 a0, a1, b0, b1;
    bool pf = (it + 1 < nit);
    if (pf) {
      long ko = (long)(it + 1) << 5;
      a0 = *(const d4*)&A[arow + ko];
      a1 = *(const d4*)&A[arow + ko + 4];
      b0 = *(const d4*)&Bt[brow + ko];
      b1 = *(const d4*)&Bt[brow + ko + 4];
    }
#pragma unroll
    for (int kk = 0; kk < 8; kk++) {
      double af = As[kk * 4 + fk][wv * 16 + fm];
#pragma unroll
      for (int nt = 0; nt < 4; nt++) {
        double bf = Bs[kk * 4 + fk][nt * 16 + fm];
        acc[nt] = __builtin_amdgcn_mfma_f64_16x16x4f64(af, bf, acc[nt], 0, 0, 0);
      }
    }
    if (pf) {
      __syncthreads();
#pragma unroll
      for (int j = 0; j < 4; j++) {
        As[lk + j][lm] = a0[j];
        As[lk + 4 + j][lm] = a1[j];
        Bs[lk + j][lm] = b0[j];
        Bs[lk + 4 + j][lm] = b1[j];
      }
      __syncthreads();
    }
  }
  double* p = P + (long)by * 131072;
#pragma unroll
  for (int nt = 0; nt < 4; nt++) {
    int gn = nt * 16 + (lane & 15);
#pragma unroll
    for (int rg = 0; rg < 4; rg++) {
      int gm = bx * 64 + wv * 16 + (lane >> 4) + 4 * rg;
      p[(long)gm * 64 + gn] = acc[nt][rg];
    }
  }
}

// bf16 MFMA GEMM body, 64x64 tile, double-buffered (16 KB within smem).
template <int EPI>
__device__ __forceinline__ void bgemm_body(char* smem, int bx, int by, int bz,
    const bf16* __restrict__ A, const bf16* __restrict__ B, void* __restrict__ C,
    int K, int ldC, long sA, long sB, long sC,
    const float* __restrict__ bias, const void* __restrict__ aux) {
  short (*Ahs)[2048] = (short(*)[2048])smem;
  short (*Bhs)[2048] = (short(*)[2048])(smem + 2 * 2048 * 2);
  const short* ah = (const short*)A + (long)bz * sA;
  const short* bh = (const short*)B + (long)bz * sB;
  int tid = threadIdx.x;
  int wv_ = tid >> 6, lane = tid & 63;
  int lrow = tid >> 2, lcol = (tid & 3) << 3;
  int lidx = lrow * 32 + lcol;
  long abase = (long)(bx * 64 + lrow) * K + lcol;
  long bbase = (long)(by * 64 + lrow) * K + lcol;
  int frow = lane & 15, fk = (lane >> 4) << 3;
  int aoff = (wv_ * 16 + frow) * 32 + fk;
  f4v acc[4] = {};
  {
    s8v avh = *(const s8v*)&ah[abase];
    s8v bvh = *(const s8v*)&bh[bbase];
    *(s8v*)&Ahs[0][lidx] = avh;
    *(s8v*)&Bhs[0][lidx] = bvh;
  }
  __syncthreads();
  int nit = K >> 5, buf = 0;
  for (int it = 0; it < nit; it++) {
    s8v avh, bvh;
    bool pf = (it + 1 < nit);
    if (pf) {
      long ko = (long)(it + 1) << 5;
      avh = *(const s8v*)&ah[abase + ko];
      bvh = *(const s8v*)&bh[bbase + ko];
    }
    s8v afh = *(const s8v*)&Ahs[buf][aoff];
#pragma unroll
    for (int nt = 0; nt < 4; nt++) {
      s8v bfh = *(const s8v*)&Bhs[buf][(nt * 16 + frow) * 32 + fk];
      acc[nt] = __builtin_amdgcn_mfma_f32_16x16x32_bf16(afh, bfh, acc[nt], 0, 0, 0);
    }
    if (pf) {
      *(s8v*)&Ahs[buf ^ 1][lidx] = avh;
      *(s8v*)&Bhs[buf ^ 1][lidx] = bvh;
      __syncthreads();
      buf ^= 1;
    }
  }
  int rb = bx * 64 + wv_ * 16 + ((lane >> 4) << 2);
#pragma unroll
  for (int nt = 0; nt < 4; nt++) {
    int gn = by * 64 + nt * 16 + (lane & 15);
#pragma unroll
    for (int rg = 0; rg < 4; rg++) {
      int gm = rb + rg;
      float v = acc[nt][rg];
      long ci = (long)bz * sC + (long)gm * ldC + gn;
      if (EPI == EPI_F32) ((float*)C)[ci] = v;
      else if (EPI == EPI_BIAS) ((float*)C)[ci] = v + bias[gn];
      else if (EPI == EPI_BRELU_BF16) ((bf16*)C)[ci] = __float2bfloat16(fmaxf(v + bias[gn], 0.f));
      else if (EPI == EPI_BF16) ((bf16*)C)[ci] = __float2bfloat16(v);
      else if (EPI == EPI_FINAL)
        ((float*)C)[ci] = v + bias[gm] + (float)((const double*)aux)[(long)gn * 512 + gm];
    }
  }
}

// Weight-cast ladder (everything NOT needed by the conv GEMM itself).
__device__ __forceinline__ void prep_elem(long i,
    const float* __restrict__ wq, const float* __restrict__ wk, const float* __restrict__ wv,
    const float* __restrict__ wst, const float* __restrict__ bst, const float* __restrict__ kc_b1,
    const float* __restrict__ kc_b2, const float* __restrict__ kc_w1, const float* __restrict__ kc_w2,
    const float* __restrict__ vc_w1, const float* __restrict__ vc_w2, const float* __restrict__ w_comb,
    const float* __restrict__ w_out, double* __restrict__ wqk64, bf16* __restrict__ wvs,
    float* __restrict__ bias2, double* __restrict__ kb1_64, double* __restrict__ kb2_64,
    double* __restrict__ kw1_64, double* __restrict__ kw2_64, bf16* __restrict__ vw1b,
    bf16* __restrict__ vw2b, bf16* __restrict__ wcombb, bf16* __restrict__ woutb) {
  if (i < 524288) {
    int r = (int)(i >> 9), c = (int)(i & 511);
    wqk64[i] = (double)((r < 512) ? wq[i] : wk[(r - 512) * 512 + c]);
    return;
  }
  i -= 524288;
  if (i < 294912) {
    int r = (int)(i >> 9), c = (int)(i & 511);
    float v = 0.f;
    if (r < 512) v = wv[i];
    else if (r < 536) v = wst[(r - 512) * 512 + c];
    wvs[i] = __float2bfloat16(v);
    if (i < 576) bias2[i] = (i >= 512 && i < 536) ? bst[i - 512] : 0.f;
    return;
  }
  i -= 294912;
  if (i < 1088) {
    if (i < 1024) kb1_64[i] = (double)kc_b1[i];
    else kb2_64[i - 1024] = (double)kc_b2[i - 1024];
    return;
  }
  i -= 1088;
  if (i < 1048576) { kw1_64[i] = (double)kc_w1[i]; return; }
  i -= 1048576;
  if (i < 65536) { kw2_64[i] = (double)kc_w2[i]; return; }
  i -= 65536;
  if (i < 1048576) { vw1b[i] = __float2bfloat16(vc_w1[i]); return; }
  i -= 1048576;
  if (i < 65536) { vw2b[i] = __float2bfloat16(vc_w2[i]); return; }
  i -= 65536;
  if (i < 262144) { wcombb[i] = __float2bfloat16(w_comb[i]); return; }
  i -= 262144;
  if (i < 262144) woutb[i] = __float2bfloat16(w_out[i]);
}
#define PREP_TOTAL 3572800l

// ---- standalone kernels ----
template <int EPI>
__global__ __launch_bounds__(256) void dgemm_bt(
    const double* __restrict__ A, const double* __restrict__ Bt, void* __restrict__ C,
    int K, int ldC, long sA, long sB, long sC, const double* __restrict__ bias, double scale) {
  __shared__ char smem[DSMEM];
  dgemm_body<EPI>(smem, blockIdx.x, blockIdx.y, blockIdx.z, A, Bt, C, K, ldC, sA, sB, sC, bias, scale);
}

template <int EPI>
__global__ __launch_bounds__(256) void gemm_bt(
    const bf16* __restrict__ A, const bf16* __restrict__ B, void* __restrict__ C,
    int K, int ldC, long sA, long sB, long sC,
    const float* __restrict__ bias, const void* __restrict__ aux) {
  __shared__ char smem[4 * 2048 * 2];
  bgemm_body<EPI>(smem, blockIdx.x, blockIdx.y, blockIdx.z, A, B, C, K, ldC, sA, sB, sC, bias, aux);
}

// conv f64 GEMM (y<8) + weight-prep casts (y>=8) in one dispatch.
__global__ __launch_bounds__(256) void k_conv_prep(
    const double* __restrict__ xt64, const double* __restrict__ win64, double* __restrict__ xs64,
    const double* __restrict__ b_in64,
    const float* __restrict__ wq, const float* __restrict__ wk, const float* __restrict__ wv,
    const float* __restrict__ wst, const float* __restrict__ bst, const float* __restrict__ kc_b1,
    const float* __restrict__ kc_b2, const float* __restrict__ kc_w1, const float* __restrict__ kc_w2,
    const float* __restrict__ vc_w1, const float* __restrict__ vc_w2, const float* __restrict__ w_comb,
    const float* __restrict__ w_out, double* __restrict__ wqk64, bf16* __restrict__ wvs,
    float* __restrict__ bias2, double* __restrict__ kb1_64, double* __restrict__ kb2_64,
    double* __restrict__ kw1_64, double* __restrict__ kw2_64, bf16* __restrict__ vw1b,
    bf16* __restrict__ vw2b, bf16* __restrict__ wcombb, bf16* __restrict__ woutb) {
  __shared__ char smem[DSMEM];
  if (blockIdx.y < 8) {
    dgemm_body<0>(smem, blockIdx.x, blockIdx.y, 0, xt64, win64, xs64, 512, 512, 0, 0, 0, b_in64, 1.0);
  } else {
    long base = (((long)(blockIdx.y - 8) * 64 + blockIdx.x) * 256) + threadIdx.x;
    for (long i = base; i < PREP_TOTAL; i += 16l * 64 * 256)
      prep_elem(i, wq, wk, wv, wst, bst, kc_b1, kc_b2, kc_w1, kc_w2, vc_w1, vc_w2, w_comb, w_out,
                wqk64, wvs, bias2, kb1_64, kb2_64, kw1_64, kw2_64, vw1b, vw2b, wcombb, woutb);
  }
}

// ---------------------------------------------------------------------------
// qk f64 GEMM (by<16) with FUSED repack epilogue (R11 keeper: qk +5µs but
// deletes repackA64's ~140MB round-trip). q-blocks (by<8): qh64 + roped rq;
// k-blocks (by 8..15): roped rk + kin64 (+k_pos). RoPE partner via shfl_xor.
// bf16 T2 GEMM at by>=16.
// ---------------------------------------------------------------------------
__global__ __launch_bounds__(256) void k_fused_qk_t2(
    const double* __restrict__ h64, const double* __restrict__ wqk,
    double* __restrict__ qh, double* __restrict__ kin,
    float* __restrict__ rq, float* __restrict__ rk, const float* __restrict__ kpos,
    const bf16* __restrict__ hbf, const bf16* __restrict__ wvs, float* __restrict__ T2,
    const float* __restrict__ bias2) {
  __shared__ char smem[DSMEM];
  if (blockIdx.y >= 16) {
    bgemm_body<EPI_BIAS>(smem, blockIdx.x, blockIdx.y - 16, 0, hbf, wvs, T2, 512, 576, 0, 0, 0, bias2,
                         nullptr);
    return;
  }
  double (*As)[73] = (double(*)[73])smem;
  double (*Bs)[73] = (double(*)[73])(smem + 32 * 73 * 8);
  int bx = blockIdx.x, by = blockIdx.y;
  int tid = threadIdx.x;
  int wv = tid >> 6, lane = tid & 63;
  int lm = tid >> 2, lk = (tid & 3) << 3;
  long arow = (long)(bx * 64 + lm) * 512 + lk;
  long brow = (long)(by * 64 + lm) * 512 + lk;
  int fm = lane & 15, fk = lane >> 4;
  d4 acc[4] = {};
  {
    d4 a0 = *(const d4*)&h64[arow], a1 = *(const d4*)&h64[arow + 4];
    d4 b0 = *(const d4*)&wqk[brow], b1 = *(const d4*)&wqk[brow + 4];
#pragma unroll
    for (int j = 0; j < 4; j++) {
      As[lk + j][lm] = a0[j];
      As[lk + 4 + j][lm] = a1[j];
      Bs[lk + j][lm] = b0[j];
      Bs[lk + 4 + j][lm] = b1[j];
    }
  }
  __syncthreads();
  for (int it = 0; it < 16; it++) {
    d4 a0, a1, b0, b1;
    bool pf = (it + 1 < 16);
    if (pf) {
      long ko = (long)(it + 1) << 5;
      a0 = *(const d4*)&h64[arow + ko];
      a1 = *(const d4*)&h64[arow + ko + 4];
      b0 = *(const d4*)&wqk[brow + ko];
      b1 = *(const d4*)&wqk[brow + ko + 4];
    }
#pragma unroll
    for (int kk = 0; kk < 8; kk++) {
      double af = As[kk * 4 + fk][wv * 16 + fm];
#pragma unroll
      for (int nt = 0; nt < 4; nt++) {
        double bf = Bs[kk * 4 + fk][nt * 16 + fm];
        acc[nt] = __builtin_amdgcn_mfma_f64_16x16x4f64(af, bf, acc[nt], 0, 0, 0);
      }
    }
    if (pf) {
      __syncthreads();
#pragma unroll
      for (int j = 0; j < 4; j++) {
        As[lk + j][lm] = a0[j];
        As[lk + 4 + j][lm] = a1[j];
        Bs[lk + j][lm] = b0[j];
        Bs[lk + 4 + j][lm] = b1[j];
      }
      __syncthreads();
    }
  }
  bool isq = by < 8;
  int h = isq ? by : by - 8;
#pragma unroll
  for (int nt = 0; nt < 4; nt++) {
    int dloc = nt * 16 + fm;
    int d2 = dloc >> 1;
    float inv = powf(10000.f, -(float)(2 * d2) / 64.f);
#pragma unroll
    for (int rg = 0; rg < 4; rg++) {
      int n = bx * 64 + wv * 16 + fk + 4 * rg;
      double v = acc[nt][rg];
      float ang = (float)n * inv;
      float sv = sinf(ang), cv = cosf(ang);
      float vf = (float)v;
      float vp = __shfl_xor(vf, 1, 64);
      float rr = (dloc & 1) ? (vf * cv + vp * sv) : (vf * cv - vp * sv);
      long oi = ((long)h * 4096 + n) * 64 + dloc;
      if (isq) {
        qh[oi] = v;
        rq[oi] = rr;
      } else {
        rk[oi] = rr;
        kin[(((long)h * 256 + (n >> 4)) * 16 + (n & 15)) * 64 + dloc] =
            v + (double)kpos[(h * 16 + (n & 15)) * 64 + dloc];
      }
    }
  }
}

// slim v-repack: T2 v-part -> vvb (f32 head-major) + vin (bf16 + v_pos).
__global__ void k_repackV(const float* __restrict__ T2, const float* __restrict__ vpos,
                          float* __restrict__ vvv, bf16* __restrict__ vin) {
  int e = blockIdx.x * 256 + threadIdx.x;  // 8*4096*64
  int d = e & 63, n = (e >> 6) & 4095, h = e >> 18;
  float v0 = T2[(long)n * 576 + h * 64 + d];
  vvv[((long)h * 4096 + n) * 64 + d] = v0;
  vin[(((long)h * 256 + (n >> 4)) * 16 + (n & 15)) * 64 + d] =
      __float2bfloat16(v0 + vpos[(h * 16 + (n & 15)) * 64 + d]);
}

__global__ __launch_bounds__(256) void k_fused_mlp1(
    const double* __restrict__ kin, const double* __restrict__ kw1, double* __restrict__ hidk,
    const double* __restrict__ kb1, const bf16* __restrict__ vin, const bf16* __restrict__ vw1,
    bf16* __restrict__ hidv, const float* __restrict__ vb1) {
  __shared__ char smem[DSMEM];
  if (blockIdx.y < 16)
    dgemm_body<1>(smem, blockIdx.x, blockIdx.y, 0, kin, kw1, hidk, 1024, 1024, 0, 0, 0, kb1, 1.0);
  else
    bgemm_body<EPI_BRELU_BF16>(smem, blockIdx.x, blockIdx.y - 16, 0, vin, vw1, hidv, 1024, 1024, 0, 0, 0,
                               vb1, nullptr);
}

__global__ __launch_bounds__(256) void k_fused_mlp2(
    const double* __restrict__ hidk, const double* __restrict__ kw2, double* __restrict__ kpart,
    const bf16* __restrict__ hidv, const bf16* __restrict__ vw2, float* __restrict__ cvc,
    const float* __restrict__ vb2) {
  __shared__ char smem[DSMEM];
  if (blockIdx.y < 8)
    dksplit_body(smem, blockIdx.x, blockIdx.y, hidk, kw2, kpart, 1024, 128);
  else
    bgemm_body<EPI_BIAS>(smem, blockIdx.x, 0, 0, hidv, vw2, cvc, 1024, 64, 0, 0, 0, vb2, nullptr);
}

// x (512,4096) f32 -> xt (4096,512) f64; y==16 slab casts win64/b_in64.
__global__ void k_transpose64(const float* __restrict__ x, double* __restrict__ xt,
                              const float* __restrict__ w_in, const float* __restrict__ b_in,
                              double* __restrict__ win64, double* __restrict__ b_in64) {
  if (blockIdx.y == 16) {
    int tid = threadIdx.y * 32 + threadIdx.x;
    long base = (long)blockIdx.x * 256 + tid;
    for (long i = base; i < 262656; i += 128l * 256) {
      if (i < 262144) win64[i] = (double)w_in[i];
      else b_in64[i - 262144] = (double)b_in[i - 262144];
    }
    return;
  }
  __shared__ float t[32][33];
  int n0 = blockIdx.x * 32, c0 = blockIdx.y * 32;
  int tx = threadIdx.x, ty = threadIdx.y;
#pragma unroll
  for (int r = ty; r < 32; r += 8) t[r][tx] = x[(long)(c0 + r) * 4096 + n0 + tx];
  __syncthreads();
#pragma unroll
  for (int r = ty; r < 32; r += 8) xt[(long)(n0 + r) * 512 + c0 + tx] = (double)t[tx][r];
}

__global__ __launch_bounds__(256) void k_rmsnorm64(const double* __restrict__ xs, const float* __restrict__ g,
                                                   double* __restrict__ h64, bf16* __restrict__ hbf) {
  int n = blockIdx.x, t = threadIdx.x;
  const double* row = xs + (long)n * 512;
  double a = row[t], b = row[t + 256];
  double ss = a * a + b * b;
#pragma unroll
  for (int m = 1; m < 64; m <<= 1) ss += __shfl_xor(ss, m, 64);
  __shared__ double red[4];
  if ((t & 63) == 0) red[t >> 6] = ss;
  __syncthreads();
  double tot = red[0] + red[1] + red[2] + red[3];
  double r = 1.0 / sqrt(tot / 512.0 + 1e-6);
  double h0 = a * r * (double)g[t], h1 = b * r * (double)g[t + 256];
  long o = (long)n * 512 + t;
  h64[o] = h0;
  h64[o + 256] = h1;
  hbf[o] = __float2bfloat16((float)h0);
  hbf[o + 256] = __float2bfloat16((float)h1);
}

// split-K partials (8x 2048x64) + cvc + mem rows -> ckb64 (8,320,64 f64), cvtb (8,64,288 bf16).
__global__ void k_repackB64(const double* __restrict__ kpart, const float* __restrict__ cvc,
                            const float* __restrict__ mem_k, const float* __restrict__ mem_v,
                            const double* __restrict__ kb2, double* __restrict__ ckb,
                            bf16* __restrict__ cvtb) {
  int g = blockIdx.x * 256 + threadIdx.x;
  if (g < 8 * 320 * 64) {
    int d = g & 63, j = (g >> 6) % 320, h = g / (320 * 64);
    double v = 0.0;
    if (j == 0) v = (double)mem_k[h * 64 + d];
    else if (j < 257) {
      long ri = ((long)h * 256 + (j - 1)) * 64 + d;
      double s = 0.0;
#pragma unroll
      for (int p = 0; p < 8; p++) s += kpart[(long)p * 131072 + ri];
      v = s + kb2[d];
    }
    ckb[g] = v;
  }
  if (g < 8 * 64 * 288) {
    int j = g % 288, d = (g / 288) & 63, h = g / (288 * 64);
    float v = 0.f;
    if (j == 0) v = mem_v[h * 64 + d];
    else if (j < 257) v = cvc[((long)h * 256 + (j - 1)) * 64 + d];
    cvtb[g] = __float2bfloat16(v);
  }
}

// Per (h,i) row: compressed softmax -> probs (bf16), and exact top-k block selection.
__global__ __launch_bounds__(256) void k_selsm(const float* __restrict__ csim, bf16* __restrict__ pb,
                                               int4* __restrict__ selb) {
  int r = blockIdx.x * 4 + (threadIdx.x >> 6);
  int lane = threadIdx.x & 63;
  int i = r & 4095;
  const float* row = csim + (long)r * 320;
  int nv = i / 16 + 1;
  float s[5], e[5];
  float mx = -INFINITY;
#pragma unroll
  for (int t = 0; t < 5; t++) {
    int j = lane + 64 * t;
    float v = (j < nv) ? row[j] : -INFINITY;
    s[t] = v;
    mx = fmaxf(mx, v);
  }
#pragma unroll
  for (int m = 1; m < 64; m <<= 1) mx = fmaxf(mx, __shfl_xor(mx, m, 64));
  float sum = 0.f;
#pragma unroll
  for (int t = 0; t < 5; t++) {
    int j = lane + 64 * t;
    e[t] = (j < nv) ? __expf(s[t] - mx) : 0.f;
    sum += e[t];
  }
  sum = wred_sum(sum);
  float rinv = 1.f / sum;
  bf16* prow = pb + (long)r * 288;
#pragma unroll
  for (int t = 0; t < 5; t++) {
    int j = lane + 64 * t;
    if (j < 288) prow[j] = __float2bfloat16((j < nv) ? e[t] * rinv : 0.f);
  }
  int nvb = i >> 1;
  int nmv = (nvb + 7) >> 3;
  float vm[4];
  float bestv = -INFINITY;
  int bestm = 0x7fffffff;
#pragma unroll
  for (int t = 0; t < 4; t++) {
    int m = lane + 64 * t;
    float v = -INFINITY;
    if (m < nmv) v = (m + 1 < nv) ? row[m + 1] : NEGF;
    vm[t] = v;
    if (v > bestv) { bestv = v; bestm = m; }
  }
#pragma unroll
  for (int mk = 1; mk < 64; mk <<= 1) {
    float ov = __shfl_xor(bestv, mk, 64);
    int om = __shfl_xor(bestm, mk, 64);
    if (ov > bestv || (ov == bestv && om < bestm)) { bestv = ov; bestm = om; }
  }
  int m0 = bestm;
  int cnt0 = min(8, nvb - 8 * m0);
  float rv = -INFINITY;
  int rm = 0x7fffffff;
#pragma unroll
  for (int t = 0; t < 4; t++) {
    int m = lane + 64 * t;
    if (m != m0 && vm[t] > rv) { rv = vm[t]; rm = m; }
  }
#pragma unroll
  for (int mk = 1; mk < 64; mk <<= 1) {
    float ov = __shfl_xor(rv, mk, 64);
    int om = __shfl_xor(rm, mk, 64);
    if (ov > rv || (ov == rv && om < rm)) { rv = ov; rm = om; }
  }
  float Ml = fmaxf(-1000.f, bestv);
  float z = 0.f;
#pragma unroll
  for (int t = 0; t < 4; t++) {
    int m = lane + 64 * t;
    if (m < nmv) z += (float)min(8, nvb - 8 * m) * expf(vm[t] - Ml);
  }
  z = wred_sum(z) + expf(-1000.f - Ml);
  int fb0 = 0, fb1 = 0, mk0 = 0, mk1 = 0;
  if (nmv > 0) {
    float sv0 = expf(bestv - Ml) / z;
    fb0 = 8 * m0;
    mk0 = sv0 > 1e-10f;
    if (cnt0 >= 2) { fb1 = fb0 + 1; mk1 = mk0; }
    else if (nmv > 1) {
      float sv1 = expf(rv - Ml) / z;
      fb1 = 8 * rm;
      mk1 = sv1 > 1e-10f;
    }
  }
  if (lane == 0) selb[r] = make_int4(fb0, fb1, mk0, mk1);
}

// Per (h,i): fine attention (selected + diag) + sliding window + gated combine.
// (R12: restored standalone — 32768 waves of TLP hide the scattered gathers;
// fusing this into the pv GEMM block (R11) cut TLP 16x and cost +38µs.)
__global__ __launch_bounds__(256) void k_fineslide(const float* __restrict__ rq, const float* __restrict__ rk,
                                                   const float* __restrict__ vv, const float* __restrict__ co,
                                                   const int4* __restrict__ selb, const float* __restrict__ T2,
                                                   bf16* __restrict__ comb) {
  int r = blockIdx.x * 4 + (threadIdx.x >> 6);
  int d = threadIdx.x & 63;
  int h = r >> 12, i = r & 4095;
  long hb = (long)h * 4096 * 64;
  float qd = rq[hb + (long)i * 64 + d];
  int4 s4 = selb[r];
  int dg = i >> 1;
  int tok[6] = {2 * s4.x, 2 * s4.x + 1, 2 * s4.y, 2 * s4.y + 1, 2 * dg, 2 * dg + 1};
  int ok6[6] = {s4.z, s4.z, s4.w, s4.w, 1, (i & 1)};
  float sim[6], val[6];
#pragma unroll
  for (int j = 0; j < 6; j++) {
    float kd = rk[hb + (long)tok[j] * 64 + d];
    val[j] = vv[hb + (long)tok[j] * 64 + d];
    float p = wred_sum(qd * kd);
    sim[j] = ok6[j] ? p * 0.125f : NEGF;
  }
  float mx = sim[0];
#pragma unroll
  for (int j = 1; j < 6; j++) mx = fmaxf(mx, sim[j]);
  float den = 0.f, fo = 0.f;
#pragma unroll
  for (int j = 0; j < 6; j++) {
    float e_ = __expf(sim[j] - mx);
    den += e_;
    fo += e_ * val[j];
  }
  fo /= den;
  float ssim[9], sval[9];
#pragma unroll
  for (int t = 0; t < 9; t++) {
    int tk = i - 8 + t;
    int okt = tk >= 0;
    int tc = okt ? tk : 0;
    float kd = rk[hb + (long)tc * 64 + d];
    sval[t] = okt ? vv[hb + (long)tc * 64 + d] : 0.f;
    float p = wred_sum(qd * kd);
    ssim[t] = okt ? p * 0.125f : NEGF;
  }
  float mx2 = ssim[8];
#pragma unroll
  for (int t = 0; t < 8; t++) mx2 = fmaxf(mx2, ssim[t]);
  float den2 = 0.f, so = 0.f;
#pragma unroll
  for (int t = 0; t < 9; t++) {
    float e_ = __expf(ssim[t] - mx2);
    den2 += e_;
    so += e_ * sval[t];
  }
  so /= den2;
  const float* gb = T2 + (long)i * 576 + 512 + h * 3;
  float g0 = 1.f / (1.f + __expf(-gb[0]));
  float g1 = 1.f / (1.f + __expf(-gb[1]));
  float g2 = 1.f / (1.f + __expf(-gb[2]));
  float cd = co[hb + (long)i * 64 + d];
  comb[(long)i * 512 + h * 64 + d] = __float2bfloat16(g0 * cd + g1 * fo + g2 * so);
}

extern "C" void kernel_launch(void* const* d_in, const int* in_sizes, int n_in, void* d_out, int out_size,
                              void* d_ws, size_t ws_size, hipStream_t stream) {
  (void)in_sizes; (void)n_in; (void)out_size; (void)ws_size;
  const float* x = (const float*)d_in[0];
  const float* w_in = (const float*)d_in[1];
  const float* b_in = (const float*)d_in[2];
  const float* g_norm = (const float*)d_in[3];
  const float* wq = (const float*)d_in[4];
  const float* wk = (const float*)d_in[5];
  const float* wv = (const float*)d_in[6];
  const float* k_pos = (const float*)d_in[7];
  const float* v_pos = (const float*)d_in[8];
  const float* mem_k = (const float*)d_in[9];
  const float* mem_v = (const float*)d_in[10];
  const float* kc_w1 = (const float*)d_in[11];
  const float* kc_b1 = (const float*)d_in[12];
  const float* kc_w2 = (const float*)d_in[13];
  const float* kc_b2 = (const float*)d_in[14];
  const float* vc_w1 = (const float*)d_in[15];
  const float* vc_b1 = (const float*)d_in[16];
  const float* vc_w2 = (const float*)d_in[17];
  const float* vc_b2 = (const float*)d_in[18];
  const float* w_strat = (const float*)d_in[19];
  const float* b_strat = (const float*)d_in[20];
  const float* w_comb = (const float*)d_in[21];
  const float* w_out = (const float*)d_in[22];
  const float* b_out = (const float*)d_in[23];

  char* wsp = (char*)d_ws;
  size_t off = 0;
  auto alloc = [&](size_t b) -> void* {
    void* p = wsp + off;
    off += (b + 255) & ~(size_t)255;
    return p;
  };
  double* xs64 = (double*)alloc(4096l * 512 * 8);
  double* h64 = (double*)alloc(4096l * 512 * 8);
  bf16* hbf = (bf16*)alloc(4096l * 512 * 2);
  double* win64 = (double*)alloc(512l * 512 * 8);
  double* wqk64 = (double*)alloc(1024l * 512 * 8);
  bf16* wvs = (bf16*)alloc(576l * 512 * 2);
  float* bias2 = (float*)alloc(576 * 4);
  double* b_in64 = (double*)alloc(512 * 8);
  double* kb1_64 = (double*)alloc(1024 * 8);
  double* kb2_64 = (double*)alloc(64 * 8);
  float* T2 = (float*)alloc(4096l * 576 * 4);
  float* csim = (float*)alloc(8l * 4096 * 320 * 4);
  double* qh64 = (double*)alloc(8l * 4096 * 64 * 8);
  float* rq = (float*)alloc(8l * 4096 * 64 * 4);
  float* rk = (float*)alloc(8l * 4096 * 64 * 4);
  float* vvb = (float*)alloc(8l * 4096 * 64 * 4);
  double* xt64 = (double*)alloc(4096l * 512 * 8);  // reused later as hidk64
  double* hidk64 = xt64;
  char* kinpb = (char*)alloc(2048l * 1024 * 8 + 2048l * 1024 * 2);  // kin64+vin, later pb
  double* kin64 = (double*)kinpb;
  bf16* vinb = (bf16*)(kinpb + 2048l * 1024 * 8);
  bf16* pb = (bf16*)kinpb;
  double* kw1_64 = (double*)alloc(1024l * 1024 * 8);
  double* kw2_64 = (double*)alloc(64l * 1024 * 8);
  bf16* vw1b = (bf16*)alloc(1024l * 1024 * 2);
  bf16* vw2b = (bf16*)alloc(64l * 1024 * 2);
  bf16* hidv = (bf16*)alloc(2048l * 1024 * 2);
  float* cvc = (float*)alloc(2048l * 64 * 4);
  double* ckb64 = (double*)alloc(8l * 320 * 64 * 8);
  bf16* cvtb = (bf16*)alloc(8l * 64 * 288 * 2);
  int4* selb = (int4*)alloc(32768l * 16);
  float* co = (float*)alloc(8l * 4096 * 64 * 4);
  bf16* comb = (bf16*)alloc(4096l * 512 * 2);
  bf16* zb = (bf16*)alloc(4096l * 512 * 2);
  bf16* wcombb = (bf16*)alloc(512l * 512 * 2);
  bf16* woutb = (bf16*)alloc(512l * 512 * 2);
  double* kpart = (double*)alloc(8l * 2048 * 64 * 8);  // split-K partials

  // ---- transpose + conv-weight cast ----
  k_transpose64<<<dim3(128, 17), dim3(32, 8), 0, stream>>>(x, xt64, w_in, b_in, win64, b_in64);
  // ---- conv (f64) + all remaining weight prep in one dispatch ----
  k_conv_prep<<<dim3(64, 24), 256, 0, stream>>>(xt64, win64, xs64, b_in64, wq, wk, wv, w_strat, b_strat,
                                                kc_b1, kc_b2, kc_w1, kc_w2, vc_w1, vc_w2, w_comb, w_out,
                                                wqk64, wvs, bias2, kb1_64, kb2_64, kw1_64, kw2_64, vw1b,
                                                vw2b, wcombb, woutb);
  k_rmsnorm64<<<4096, 256, 0, stream>>>(xs64, g_norm, h64, hbf);
  // ---- qk GEMM with fused repack epilogue (+ T2 bf16 GEMM) ----
  k_fused_qk_t2<<<dim3(64, 25, 1), 256, 0, stream>>>(h64, wqk64, qh64, kin64, rq, rk, k_pos, hbf, wvs, T2,
                                                     bias2);
  k_repackV<<<8192, 256, 0, stream>>>(T2, v_pos, vvb, vinb);
  k_fused_mlp1<<<dim3(32, 32, 1), 256, 0, stream>>>(kin64, kw1_64, hidk64, kb1_64, vinb, vw1b, hidv, vc_b1);
  k_fused_mlp2<<<dim3(32, 9, 1), 256, 0, stream>>>(hidk64, kw2_64, kpart, hidv, vw2b, cvc, vc_b2);
  k_repackB64<<<640, 256, 0, stream>>>(kpart, cvc, mem_k, mem_v, kb2_64, ckb64, cvtb);
  dgemm_bt<2><<<dim3(64, 5, 8), 256, 0, stream>>>(qh64, ckb64, csim, 64, 320, 4096l * 64, 320l * 64,
                                                  4096l * 320, nullptr, 0.125);
  // ---- selection + attention combine (standalone fineslide, full TLP) ----
  k_selsm<<<8192, 256, 0, stream>>>(csim, pb, selb);
  gemm_bt<EPI_F32><<<dim3(64, 1, 8), 256, 0, stream>>>(pb, cvtb, co, 288, 64, 4096l * 288, 64l * 288,
                                                       4096l * 64, nullptr, nullptr);
  k_fineslide<<<8192, 256, 0, stream>>>(rq, rk, vvb, co, selb, T2, comb);
  // ---- output mixing ----
  gemm_bt<EPI_BF16><<<dim3(64, 8, 1), 256, 0, stream>>>(comb, wcombb, zb, 512, 512, 0, 0, 0, nullptr, nullptr);
  gemm_bt<EPI_FINAL><<<dim3(8, 64, 1), 256, 0, stream>>>(woutb, zb, d_out, 512, 4096, 0, 0, 0, b_out, xs64);
}